// Round 11
// baseline (48218.658 us; speedup 1.0000x reference)
//
#include <hip/hip_runtime.h>

// ---------------------------------------------------------------------------
// BBCU binary SR network, round 11 — f32 bit-exact attempt, Eigen/XLA-CPU
// conv order: NHWC-canonicalized im2col, k-order (ky, kx, ci) with ci
// FASTEST, single accumulator FMA chain per output, k ascending.
// All elementwise ops in exact reference formula order (f32 RNE), dirty
// surrogate values (acts/weights), numpy pairwise mean for scale.
// Zero-pad taps are FMA no-ops -> boundary skip is bit-identical.
// ---------------------------------------------------------------------------

__device__ inline float fadd(float a, float b) { return __fadd_rn(a, b); }
__device__ inline float fmul(float a, float b) { return __fmul_rn(a, b); }
__device__ inline float fsub(float a, float b) { return __fsub_rn(a, b); }

// binary_act forward, exact f32 op-order emulation (incl. surrogate dirt)
__device__ inline float bact(float xp) {
  float sgn = xp > 0.f ? 1.f : (xp < 0.f ? -1.f : 0.f);
  float xx = fmul(xp, xp);
  float tx = fmul(2.0f, xp);
  float out3;
  if (xp < -1.f)      out3 = -1.f;
  else if (xp < 0.f)  out3 = fadd(xx, tx);     // x^2 + 2x
  else if (xp < 1.f)  out3 = fadd(-xx, tx);    // -x^2 + 2x
  else                out3 = 1.f;
  return fadd(fsub(sgn, out3), out3);          // dirty activation
}

// numpy pairwise sum of |p[0..n)| (exact numpy algorithm, f32)
__device__ float pw_abs_sum(const float* p, int n) {
  if (n <= 8) {
    float s = fabsf(p[0]);
    for (int i = 1; i < n; i++) s = fadd(s, fabsf(p[i]));
    return s;
  }
  if (n <= 128) {
    float r[8];
#pragma unroll
    for (int q = 0; q < 8; q++) r[q] = fabsf(p[q]);
    int i;
    for (i = 8; i + 8 <= n; i += 8)
#pragma unroll
      for (int q = 0; q < 8; q++) r[q] = fadd(r[q], fabsf(p[i + q]));
    float res = fadd(fadd(fadd(r[0], r[1]), fadd(r[2], r[3])),
                     fadd(fadd(r[4], r[5]), fadd(r[6], r[7])));
    for (; i < n; i++) res = fadd(res, fabsf(p[i]));
    return res;
  }
  int n2 = (n / 2) & ~7;
  return fadd(pw_abs_sum(p, n2), pw_abs_sum(p + n2, n - n2));
}

// --- diagnostic ------------------------------------------------------------
__global__ __launch_bounds__(256) void diag_kernel(float* __restrict__ out,
                                                   int n, float tag) {
  int idx = blockIdx.x * 256 + threadIdx.x;
  if (idx < n) out[idx] = (idx == 0) ? tag : 0.f;
}

// --- binarize_weight fwd, exact f32: dirty = (bw - cw) + cw ----------------
__global__ __launch_bounds__(64) void binw_kernel(
    const float* __restrict__ w, float* __restrict__ wt, int nch) {
  int ch = blockIdx.x * 64 + threadIdx.x;
  if (ch >= nch) return;
  const float* wc = w + (size_t)ch * 576;
  float S = pw_abs_sum(wc, 576);
  float scale = __fdiv_rn(S, 576.0f);
  float* o = wt + (size_t)ch * 576;
  for (int k = 0; k < 576; k++) {
    float wv = wc[k];
    float sg = wv > 0.f ? 1.f : (wv < 0.f ? -1.f : 0.f);
    float bw = fmul(scale, sg);
    float cw = fminf(fmaxf(wv, -1.f), 1.f);
    o[k] = fadd(fsub(bw, cw), cw);
  }
}

// --- conv_first (one n): f32, (ky,kx,ci) FMA chain -------------------------
__global__ __launch_bounds__(256) void conv_first_kernel(
    const float* __restrict__ x,      // (3,128,128)
    const float* __restrict__ w, const float* __restrict__ b,
    float* __restrict__ out) {        // (64,128,128)
  int idx = blockIdx.x * 256 + threadIdx.x;
  int gx = idx & 127;
  int gy = (idx >> 7) & 127;
  int co = idx >> 14;
  const float* wp = w + co * 27;
  float acc = 0.f;
  for (int ky = 0; ky < 3; ky++) {             // NHWC patch: ky slowest
    int yy = gy + ky - 1;
    if (yy < 0 || yy > 127) continue;          // pad taps: fma(0,w,a)==a
    for (int kx = 0; kx < 3; kx++) {
      int xx = gx + kx - 1;
      if (xx < 0 || xx > 127) continue;
      for (int ci = 0; ci < 3; ci++)           // ci fastest
        acc = fmaf(x[ci * 16384 + yy * 128 + xx],
                   wp[ci * 9 + ky * 3 + kx], acc);
    }
  }
  float wb = fadd(acc, b[co]);
  out[idx] = wb >= 0.f ? wb : fmul(0.1f, wb);
}

// --- binary conv (dirty f32, (ky,kx,ci) FMA chain) + rprelu + residual -----
// One batch sample. Block: 256 thr = 8x8 px * 4 cog; 8 out-ch per block;
// each thread 1 pixel, 2 consecutive co. All 64 ci resident in LDS.
template <int H, int W, int COUT, bool UPSHUF>
__global__ __launch_bounds__(256) void binconv_kernel(
    const float* __restrict__ feat,   // (64,H,W)
    const float* __restrict__ wt,     // (COUT,576) dirty f32 weights (OIHW k)
    const float* __restrict__ move,   // (64)
    const float* __restrict__ pa, const float* __restrict__ pb1,
    const float* __restrict__ pb2,    // (COUT)
    float* __restrict__ out)          // bbcu: (64,H,W); up: (64,2H,2W)
{
  __shared__ float s_a[64][10][12];   // dirty acts: 64 ci x 10x10 halo tile
  __shared__ float s_w[8][576];       // 8 co x 576 dirty weights

  int t = threadIdx.x;
  int px = t & 7, py = (t >> 3) & 7, cog = t >> 6;   // wave-uniform cog
  int x0 = blockIdx.x * 8, y0 = blockIdx.y * 8;
  int co_base = blockIdx.z * 8;

  for (int i = t; i < 64 * 100; i += 256) {
    int ci = i / 100;
    int rem = i - ci * 100;
    int r = rem / 10, c = rem - r * 10;
    int gy = y0 - 1 + r, gx = x0 - 1 + c;
    float a = 0.f;                    // conv zero-pads the activation tensor
    if (gy >= 0 && gy < H && gx >= 0 && gx < W) {
      float v = fadd(feat[((size_t)ci * H + gy) * W + gx], move[ci]);
      a = bact(v);
    }
    s_a[ci][r][c] = a;
  }
  {
    const float* wp = wt + (size_t)co_base * 576;
    for (int i = t; i < 8 * 576; i += 256) (&s_w[0][0])[i] = wp[i];
  }
  __syncthreads();

  int c0 = cog * 2, c1 = c0 + 1;
  float acc0 = 0.f, acc1 = 0.f;
  // single FMA chain per output, k ascending in (ky, kx, ci), ci fastest
  for (int ky = 0; ky < 3; ky++)
    for (int kx = 0; kx < 3; kx++) {
      int tap = ky * 3 + kx;
      for (int ci = 0; ci < 64; ci++) {
        float a = s_a[ci][py + ky][px + kx];
        int k = ci * 9 + tap;                  // OIHW storage index
        acc0 = fmaf(a, s_w[c0][k], acc0);
        acc1 = fmaf(a, s_w[c1][k], acc1);
      }
    }

  // epilogue: rprelu + residual, exact f32 formula order
  int gy = y0 + py, gx = x0 + px;
  float accs[2] = {acc0, acc1};
#pragma unroll
  for (int q = 0; q < 2; q++) {
    int co_abs = co_base + cog * 2 + q;
    float t1 = fadd(accs[q], pb1[co_abs]);
    float t2 = t1 >= 0.f ? t1 : fmul(pa[co_abs], t1);
    float t3 = fadd(t2, pb2[co_abs]);
    if (!UPSHUF) {
      size_t fi = ((size_t)co_abs * H + gy) * W + gx;
      out[fi] = fadd(t3, feat[fi]);
    } else {
      float res = feat[((size_t)(co_abs & 63) * H + gy) * W + gx];
      int oc = co_abs >> 2, dr = (co_abs >> 1) & 1, dc = co_abs & 1;
      size_t oi = ((size_t)oc * (2 * H) + (2 * gy + dr)) * (2 * W)
                  + (2 * gx + dc);
      out[oi] = fadd(t3, res);
    }
  }
}

// --- conv_last (one n): leaky f32 -> conv (ky,kx,ci) FMA chain + bias,
//     resize base (f32 rows-then-cols), final f32 add -----------------------
__global__ __launch_bounds__(256) void conv_last_kernel(
    const float* __restrict__ V,      // (64,512,512)
    const float* __restrict__ w, const float* __restrict__ b,
    const float* __restrict__ x,      // (3,128,128)
    float* __restrict__ out) {        // (3,512,512)
  int idx = blockIdx.x * 256 + threadIdx.x;
  int gx = idx & 511;
  int gy = idx >> 9;
  float acc0 = 0.f, acc1 = 0.f, acc2 = 0.f;
  for (int ky = 0; ky < 3; ky++) {             // (ky,kx,ci), ci fastest
    int yy = gy + ky - 1;
    if (yy < 0 || yy > 511) continue;
    for (int kx = 0; kx < 3; kx++) {
      int xx = gx + kx - 1;
      if (xx < 0 || xx > 511) continue;
      int tap = ky * 3 + kx;
      for (int ci = 0; ci < 64; ci++) {
        float v = V[((size_t)ci << 18) + (yy << 9) + xx];
        v = v >= 0.f ? v : fmul(0.1f, v);      // leaky (elementwise, f32)
        int k = ci * 9 + tap;
        acc0 = fmaf(v, w[k], acc0);
        acc1 = fmaf(v, w[576 + k], acc1);
        acc2 = fmaf(v, w[1152 + k], acc2);
      }
    }
  }
  float o0 = fadd(acc0, b[0]);
  float o1 = fadd(acc1, b[1]);
  float o2 = fadd(acc2, b[2]);
  // resize: half-pixel bilinear, rows pass then cols pass, f32;
  // edge renormalization == single tap with weight exactly 1.0
  float sy = (gy + 0.5f) * 0.25f - 0.5f;
  float sx = (gx + 0.5f) * 0.25f - 0.5f;
  int iy0 = (int)floorf(sy);
  int ix0 = (int)floorf(sx);
  float fy = sy - (float)iy0, fx = sx - (float)ix0;
  int y0c = min(max(iy0, 0), 127), y1c = min(max(iy0 + 1, 0), 127);
  int x0c = min(max(ix0, 0), 127), x1c = min(max(ix0 + 1, 0), 127);
  float accs[3] = {o0, o1, o2};
#pragma unroll
  for (int co = 0; co < 3; co++) {
    const float* xp = x + (size_t)co * 16384;
    float c00 = xp[y0c * 128 + x0c], c01 = xp[y0c * 128 + x1c];
    float c10 = xp[y1c * 128 + x0c], c11 = xp[y1c * 128 + x1c];
    float v0, v1;
    if (y1c == y0c) { v0 = fmul(1.f, c00); v1 = fmul(1.f, c01); }
    else {
      v0 = fadd(fmul(1.f - fy, c00), fmul(fy, c10));
      v1 = fadd(fmul(1.f - fy, c01), fmul(fy, c11));
    }
    float base = (x1c == x0c) ? fmul(1.f, v0)
                              : fadd(fmul(1.f - fx, v0), fmul(fx, v1));
    out[((size_t)co << 18) + (gy << 9) + gx] = fadd(accs[co], base);
  }
}

extern "C" void kernel_launch(void* const* d_in, const int* in_sizes, int n_in,
                              void* d_out, int out_size, void* d_ws,
                              size_t ws_size, hipStream_t stream) {
  const float* x         = (const float*)d_in[0];
  const float* cf_w      = (const float*)d_in[1];
  const float* cf_b      = (const float*)d_in[2];
  const float* body_move = (const float*)d_in[3];
  const float* body_w    = (const float*)d_in[4];
  const float* body_a    = (const float*)d_in[5];
  const float* body_b1   = (const float*)d_in[6];
  const float* body_b2   = (const float*)d_in[7];
  const float* up1_move  = (const float*)d_in[8];
  const float* up1_w     = (const float*)d_in[9];
  const float* up1_a     = (const float*)d_in[10];
  const float* up1_b1    = (const float*)d_in[11];
  const float* up1_b2    = (const float*)d_in[12];
  const float* up2_move  = (const float*)d_in[13];
  const float* up2_w     = (const float*)d_in[14];
  const float* up2_a     = (const float*)d_in[15];
  const float* up2_b1    = (const float*)d_in[16];
  const float* up2_b2    = (const float*)d_in[17];
  const float* hr_move   = (const float*)d_in[18];
  const float* hr_w      = (const float*)d_in[19];
  const float* hr_a      = (const float*)d_in[20];
  const float* hr_b1     = (const float*)d_in[21];
  const float* hr_b2     = (const float*)d_in[22];
  const float* cl_w      = (const float*)d_in[23];
  const float* cl_b      = (const float*)d_in[24];
  float* out = (float*)d_out;

  const size_t M = 1024 * 1024;
  if (ws_size < 160 * M) {
    diag_kernel<<<(out_size + 255) / 256, 256, 0, stream>>>(
        out, out_size, (float)(ws_size >> 20));
    return;
  }

  // ws layout (158 MiB), per-batch-sample recycled, f32:
  //   A [0,4M)    conv_first out / body ping (64,128,128)
  //   B [4,8M)    body pong
  //   P [8,24M)   up1 out (64,256,256)
  //   U [24,88M)  up2 out (64,512,512)
  //   V [88,152M) hr out  (64,512,512)
  //   WT[152M,..) dirty f32 weights (2624 x 576, ~5.8 MiB)
  char* ws = (char*)d_ws;
  float* A = (float*)(ws + 0);
  float* B = (float*)(ws + 4 * M);
  float* P = (float*)(ws + 8 * M);
  float* U = (float*)(ws + 24 * M);
  float* V = (float*)(ws + 88 * M);
  float* WT = (float*)(ws + 152 * M);
  float* body_wt = WT;                          // 2048*576
  float* up1_wt  = body_wt + (size_t)2048 * 576;
  float* up2_wt  = up1_wt + (size_t)256 * 576;
  float* hr_wt   = up2_wt + (size_t)256 * 576;

  binw_kernel<<<32, 64, 0, stream>>>(body_w, body_wt, 2048);
  binw_kernel<<<4, 64, 0, stream>>>(up1_w, up1_wt, 256);
  binw_kernel<<<4, 64, 0, stream>>>(up2_w, up2_wt, 256);
  binw_kernel<<<1, 64, 0, stream>>>(hr_w, hr_wt, 64);

  for (int n = 0; n < 4; n++) {
    const float* xn = x + (size_t)n * 3 * 16384;
    conv_first_kernel<<<4096, 256, 0, stream>>>(xn, cf_w, cf_b, A);

    float* bin = A;
    float* bout = B;
    for (int u = 0; u < 32; u++) {
      binconv_kernel<128, 128, 64, false>
          <<<dim3(16, 16, 8), 256, 0, stream>>>(
              bin, body_wt + (size_t)u * 64 * 576, body_move + u * 64,
              body_a + u * 64, body_b1 + u * 64, body_b2 + u * 64, bout);
      float* tmp = bin; bin = bout; bout = tmp;
    }
    // body output in A (even swap count)
    binconv_kernel<128, 128, 256, true>
        <<<dim3(16, 16, 32), 256, 0, stream>>>(
            A, up1_wt, up1_move, up1_a, up1_b1, up1_b2, P);
    binconv_kernel<256, 256, 256, true>
        <<<dim3(32, 32, 32), 256, 0, stream>>>(
            P, up2_wt, up2_move, up2_a, up2_b1, up2_b2, U);
    binconv_kernel<512, 512, 64, false>
        <<<dim3(64, 64, 8), 256, 0, stream>>>(
            U, hr_wt, hr_move, hr_a, hr_b1, hr_b2, V);
    conv_last_kernel<<<1024, 256, 0, stream>>>(
        V, cl_w, cl_b, xn, out + (size_t)n * 3 * 262144);
  }
}